// Round 13
// baseline (2022.719 us; speedup 1.0000x reference)
//
#include <hip/hip_runtime.h>
#include <cstdint>
#include <cstddef>

// CCDecoder: 16-step input-feeding LSTM + Luong attention decoder.
// B=256, S=512, T=16, H=1024, E=512.
// R13 = R12 with W_in fused into the attn kernel (3 nodes/step, 50 total):
//   - attn kernel blocks 0..63 first run the W_in GEMM tile (4-wave body,
//     waves 4-7 run a barrier-matching loop), publish per-tile tflags.
//   - every block waits (capped spin) on the 16 tflags of its row's m-tile;
//     on timeout it computes the target row itself (GEMV fallback) ->
//     deadlock-impossible, co-residency is an optimization only.
//   - per-step wtgt/pacc/pml buffers: consumers only read addresses never
//     cached by this kernel -> no stale-line hazards (XCD L2 non-coherent;
//     producer release does wbl2).
//   - rows length-sorted (bitonic in convert): longest rows -> blocks that
//     start attn immediately; 32 shortest -> the W_in blocks (0..63).
//   Proven pieces kept: gates/W_out gemm (NBUF=6, depth-4, vmcnt 16/12/8/4/0),
//   fused LSTM epilogue, pair-split online-softmax attn, h ping-pong.

#define B_ 256
#define S_ 512
#define T_ 16
#define H_ 1024
#define E_ 512
#define NBUF 6

typedef unsigned short u16;
using short8 = __attribute__((ext_vector_type(8))) short;
using f32x4  = __attribute__((ext_vector_type(4))) float;

__device__ __forceinline__ float bf2f(u16 u) {
  union { uint32_t i; float f; } v; v.i = ((uint32_t)u) << 16; return v.f;
}
__device__ __forceinline__ u16 f2bf(float f) {
  union { uint32_t i; float f; } v; v.f = f;
  uint32_t r = v.i + 0x7fffu + ((v.i >> 16) & 1u);
  return (u16)(r >> 16);
}
__device__ __forceinline__ ushort4 cvt4bf(float4 v) {
  ushort4 o; o.x = f2bf(v.x); o.y = f2bf(v.y); o.z = f2bf(v.z); o.w = f2bf(v.w);
  return o;
}
__device__ __forceinline__ float sigmoidf_(float x) { return 1.f / (1.f + __expf(-x)); }

__device__ __forceinline__ void gload_lds16(const void* g, void* l) {
  __builtin_amdgcn_global_load_lds(
      (const __attribute__((address_space(1))) void*)g,
      (__attribute__((address_space(3))) void*)l, 16, 0, 0);
}

__device__ __forceinline__ void st_flag(int* p) {
  __hip_atomic_store(p, 1, __ATOMIC_RELEASE, __HIP_MEMORY_SCOPE_AGENT);
}

struct Reg3 { const u16* A; int lda; const u16* B; int ldb; int kt; };

// ---------------------------------------------------------------- GEMM (stand-alone)
// 64x64 tile, 256 thr = 4 waves (2x2), 32x32 acc/wave. NBUF=6, 4-deep
// prefetch, vmcnt(16/12/8/4/0) (4 loads/thread/stage). XOR swizzle both sides.
template <int EPI>   // 2: tanh->fp32 out+bf16 Cb  3: fused LSTM
__global__ __launch_bounds__(256) void gemm_k(Reg3 r0, Reg3 r1, Reg3 r2,
                                              int nmb,
                                              float* __restrict__ Cf,
                                              u16* __restrict__ Cb,
                                              const float* __restrict__ bsum,
                                              float* __restrict__ cst,
                                              u16* __restrict__ hbfo,
                                              float* __restrict__ outHC,
                                              const int tstep) {
  __shared__ u16 smA[NBUF][4096];
  __shared__ u16 smB[NBUF][4096];
  const int tid = threadIdx.x;
  const int lane = tid & 63;
  const int wave = tid >> 6;
  const int wm = wave >> 1, wn = wave & 1;
  const int m0 = (blockIdx.x % nmb) * 64;
  const int n0 = (blockIdx.x / nmb) * 64;
  const int row16 = lane & 15;
  const int kg = lane >> 4;
  const int nt = r0.kt + r1.kt + r2.kt;

  auto stage = [&](int ti, int buf) {
    const int k01 = r0.kt + r1.kt;
    const u16* Ap = (ti < r0.kt) ? r0.A : (ti < k01) ? r1.A : r2.A;
    const u16* Bp = (ti < r0.kt) ? r0.B : (ti < k01) ? r1.B : r2.B;
    const int lda = (ti < r0.kt) ? r0.lda : (ti < k01) ? r1.lda : r2.lda;
    const int ldb = (ti < r0.kt) ? r0.ldb : (ti < k01) ? r1.ldb : r2.ldb;
    const int base = (ti < r0.kt) ? 0 : (ti < k01) ? r0.kt : k01;
    const int kr = (ti - base) << 6;
#pragma unroll
    for (int j = 0; j < 2; ++j) {
      const int c = j * 256 + tid;
      const int row = c >> 3, q = c & 7;
      gload_lds16(Ap + (size_t)(m0 + row) * lda + kr + ((q ^ (row & 7)) << 3),
                  (char*)&smA[buf][0] + (size_t)(j * 256 + wave * 64) * 16);
    }
#pragma unroll
    for (int j = 0; j < 2; ++j) {
      const int c = j * 256 + tid;
      const int row = c >> 3, q = c & 7;
      gload_lds16(Bp + (size_t)(n0 + row) * ldb + kr + ((q ^ (row & 7)) << 3),
                  (char*)&smB[buf][0] + (size_t)(j * 256 + wave * 64) * 16);
    }
  };

  f32x4 acc[2][2] = {};
  stage(0, 0);
  if (nt > 1) stage(1, 1);
  if (nt > 2) stage(2, 2);
  if (nt > 3) stage(3, 3);
  for (int ti = 0; ti < nt; ++ti) {
    const int buf = ti % NBUF;
    if (ti + 4 < nt) {
      stage(ti + 4, (ti + 4) % NBUF);
      asm volatile("s_waitcnt vmcnt(16)" ::: "memory");
    } else if (ti + 3 < nt) {
      asm volatile("s_waitcnt vmcnt(12)" ::: "memory");
    } else if (ti + 2 < nt) {
      asm volatile("s_waitcnt vmcnt(8)" ::: "memory");
    } else if (ti + 1 < nt) {
      asm volatile("s_waitcnt vmcnt(4)" ::: "memory");
    } else {
      asm volatile("s_waitcnt vmcnt(0)" ::: "memory");
    }
    __builtin_amdgcn_s_barrier();
    __builtin_amdgcn_sched_barrier(0);
#pragma unroll
    for (int ks = 0; ks < 2; ++ks) {
      short8 af[2], bfr[2];
#pragma unroll
      for (int mi = 0; mi < 2; ++mi) {
        const int R = wm * 32 + mi * 16 + row16;
        af[mi] = *(const short8*)((const char*)&smA[buf][0] +
                                  (size_t)(((R << 3) | ((ks * 4 + kg) ^ (R & 7))) << 4));
      }
#pragma unroll
      for (int ni = 0; ni < 2; ++ni) {
        const int R = wn * 32 + ni * 16 + row16;
        bfr[ni] = *(const short8*)((const char*)&smB[buf][0] +
                                   (size_t)(((R << 3) | ((ks * 4 + kg) ^ (R & 7))) << 4));
      }
      asm volatile("s_waitcnt lgkmcnt(0)" ::: "memory");
      __builtin_amdgcn_sched_barrier(0);
#pragma unroll
      for (int mi = 0; mi < 2; ++mi)
#pragma unroll
        for (int ni = 0; ni < 2; ++ni)
          acc[mi][ni] = __builtin_amdgcn_mfma_f32_16x16x32_bf16(af[mi], bfr[ni], acc[mi][ni], 0, 0, 0);
      __builtin_amdgcn_sched_barrier(0);
    }
  }
  // C/D layout: col = lane&15, row = (lane>>4)*4 + r  [m89-verified]
#pragma unroll
  for (int mi = 0; mi < 2; ++mi) {
#pragma unroll
    for (int ni = 0; ni < 2; ++ni) {
#pragma unroll
      for (int r = 0; r < 4; ++r) {
        const int row = m0 + wm * 32 + mi * 16 + (kg << 2) + r;
        const int col = n0 + wn * 32 + ni * 16 + row16;
        float v = acc[mi][ni][r];
        if (EPI == 2) {
          float tv = tanhf(v);
          Cf[(size_t)row * (T_ * H_) + (size_t)tstep * H_ + col] = tv;
          Cb[row * H_ + col] = f2bf(tv);
        } else {
          v += bsum[col];
          float v1 = __shfl_xor(v, 1);
          float v2 = __shfl_xor(v, 2);
          float v3 = __shfl_xor(v, 3);
          if ((lane & 3) == 0) {
            const int u = col >> 2;
            float iv = sigmoidf_(v);
            float fv = sigmoidf_(v1);
            float gv = tanhf(v2);
            float ov = sigmoidf_(v3);
            float cn = fv * cst[row * H_ + u] + iv * gv;
            float hn = ov * tanhf(cn);
            cst[row * H_ + u] = cn;
            hbfo[row * H_ + u] = f2bf(hn);
            if (outHC) {
              outHC[row * H_ + u] = hn;
              outHC[B_ * H_ + row * H_ + u] = cn;
            }
          }
        }
      }
    }
  }
}

// ---------------------------------------------------------------- fused W_in + attention
__device__ __forceinline__ int fidx(int lane, int j) {
  return (j << 6) + ((lane + (j << 2)) & 63);
}

struct AP {
  const u16* hrow;   // h (A of W_in, fallback GEMV)
  const u16* Win;    // W_in bf16 (row-major [n][k])
  u16* tgt;          // per-step target buffer
  const u16* ctxc;
  const int* woffs;
  const int* src_len;
  const int* worder;
  u16* wwbf;
  float* pacc;       // per-step pair partials
  float* pml;
  int* tflag;        // 64 (4m x 16n)
  int* pflag;        // 256
};

union SMemF {
  struct { u16 A[4][4096]; u16 B[4][4096]; } g;                        // 64 KB
  struct { float facc[7][1024]; float fm[8]; float fl[8];
           float tgtf[1024]; int ok; } a;                              // ~33 KB
};

__global__ __launch_bounds__(512, 4) void attn_fused(AP P) {
  __shared__ SMemF sm;
  const int tid = threadIdx.x;
  const int bid = blockIdx.x;
  const int lane = tid & 63;
  const int wave = tid >> 6;

  // ---------- phase A: W_in GEMM tiles (blocks 0..63) ----------
  if (bid < 64) {
    const int m0 = (bid & 3) * 64;
    const int n0 = (bid >> 2) * 64;
    if (tid < 256) {
      const int wv = tid >> 6;            // 0..3
      const int wm = wv >> 1, wn = wv & 1;
      const int row16 = lane & 15, kg = lane >> 4;
      auto stage = [&](int ti, int buf) {
        const int kr = ti << 6;
#pragma unroll
        for (int j = 0; j < 2; ++j) {     // A: h rows
          const int c = j * 256 + tid;
          const int r = c >> 3, q = c & 7;
          gload_lds16(P.hrow + (size_t)(m0 + r) * H_ + kr + ((q ^ (r & 7)) << 3),
                      (char*)&sm.g.A[buf][0] + (size_t)(j * 256 + wv * 64) * 16);
        }
#pragma unroll
        for (int j = 0; j < 2; ++j) {     // B: W_in rows
          const int c = j * 256 + tid;
          const int r = c >> 3, q = c & 7;
          gload_lds16(P.Win + (size_t)(n0 + r) * H_ + kr + ((q ^ (r & 7)) << 3),
                      (char*)&sm.g.B[buf][0] + (size_t)(j * 256 + wv * 64) * 16);
        }
      };
      f32x4 acc[2][2] = {};
      stage(0, 0);
      stage(1, 1);
      for (int ti = 0; ti < 16; ++ti) {
        const int buf = ti & 3;
        if (ti + 2 < 16) {                // depth-2/NBUF-4: R8-proven safe
          stage(ti + 2, (ti + 2) & 3);
          asm volatile("s_waitcnt vmcnt(8)" ::: "memory");
        } else if (ti + 1 < 16) {
          asm volatile("s_waitcnt vmcnt(4)" ::: "memory");
        } else {
          asm volatile("s_waitcnt vmcnt(0)" ::: "memory");
        }
        __builtin_amdgcn_s_barrier();
        __builtin_amdgcn_sched_barrier(0);
#pragma unroll
        for (int ks = 0; ks < 2; ++ks) {
          short8 af[2], bfr[2];
#pragma unroll
          for (int mi = 0; mi < 2; ++mi) {
            const int R = wm * 32 + mi * 16 + row16;
            af[mi] = *(const short8*)((const char*)&sm.g.A[buf][0] +
                                      (size_t)(((R << 3) | ((ks * 4 + kg) ^ (R & 7))) << 4));
          }
#pragma unroll
          for (int ni = 0; ni < 2; ++ni) {
            const int R = wn * 32 + ni * 16 + row16;
            bfr[ni] = *(const short8*)((const char*)&sm.g.B[buf][0] +
                                       (size_t)(((R << 3) | ((ks * 4 + kg) ^ (R & 7))) << 4));
          }
          asm volatile("s_waitcnt lgkmcnt(0)" ::: "memory");
          __builtin_amdgcn_sched_barrier(0);
#pragma unroll
          for (int mi = 0; mi < 2; ++mi)
#pragma unroll
            for (int ni = 0; ni < 2; ++ni)
              acc[mi][ni] = __builtin_amdgcn_mfma_f32_16x16x32_bf16(af[mi], bfr[ni], acc[mi][ni], 0, 0, 0);
          __builtin_amdgcn_sched_barrier(0);
        }
      }
#pragma unroll
      for (int mi = 0; mi < 2; ++mi)
#pragma unroll
        for (int ni = 0; ni < 2; ++ni)
#pragma unroll
          for (int r = 0; r < 4; ++r) {
            const int row = m0 + wm * 32 + mi * 16 + (kg << 2) + r;
            const int col = n0 + wn * 32 + ni * 16 + row16;
            P.tgt[row * H_ + col] = f2bf(acc[mi][ni][r]);
          }
    } else {
      for (int i = 0; i < 16; ++i) __builtin_amdgcn_s_barrier();  // barrier match
    }
    __syncthreads();   // drains stores (compiler waitcnt) across all waves
    if (tid == 0) st_flag(P.tflag + (bid & 3) * 16 + (bid >> 2));
  }

  // ---------- phase B: attention (all 512 blocks; pair p = halves of a row) ----------
  const int p = bid >> 1;
  const int half = bid & 1;
  const int row = P.worder[p];
  const int len = P.src_len[row];
  const int len2 = (len + 1) >> 1;
  const u16* cb = P.ctxc + ((size_t)P.woffs[row] << 10);
  const int mt = row >> 6;

  {  // wait for target m-tile (16 tflags), capped, fallback-safe
    int got = 1;
    if (wave == 0) {
      if (lane < 16) {
        int* tf = P.tflag + mt * 16 + lane;
        unsigned c = 0;
        while (__hip_atomic_load(tf, __ATOMIC_RELAXED, __HIP_MEMORY_SCOPE_AGENT) == 0 &&
               c < (1u << 16)) {
          __builtin_amdgcn_s_sleep(4);
          ++c;
        }
        got = (__hip_atomic_load(tf, __ATOMIC_ACQUIRE, __HIP_MEMORY_SCOPE_AGENT) != 0) ? 1 : 0;
      }
      unsigned long long mk = __ballot(got != 0);
      if (lane == 0) sm.a.ok = ((mk & 0xFFFFull) == 0xFFFFull) ? 1 : 0;
    }
    __syncthreads();
  }
  const int allok = sm.a.ok;
  if (!allok) {   // GEMV fallback (correct under any scheduling; never in practice)
    const u16* hr = P.hrow + (size_t)row * H_;
    for (int j = tid; j < H_; j += 512) {
      float a = 0.f;
      const u16* wr = P.Win + (size_t)j * H_;
      for (int k = 0; k < H_; ++k) a += bf2f(hr[k]) * bf2f(wr[k]);
      sm.a.tgtf[j] = bf2f(f2bf(a));
    }
    __syncthreads();
  }

  float tg[16];
  if (allok) {
    const u16* tp = P.tgt + row * H_ + lane * 16;
    short8 v1 = *(const short8*)tp;
    short8 v2 = *(const short8*)(tp + 8);
#pragma unroll
    for (int j = 0; j < 8; ++j) { tg[j] = bf2f((u16)v1[j]); tg[8 + j] = bf2f((u16)v2[j]); }
  } else {
#pragma unroll
    for (int j = 0; j < 16; ++j) tg[j] = sm.a.tgtf[lane * 16 + j];
  }

  float m = -1e30f, l = 0.f;
  float acc[16];
#pragma unroll
  for (int j = 0; j < 16; ++j) acc[j] = 0.f;

  auto process = [&](int s) {
    const u16* cr = cb + ((size_t)s << 10) + (lane << 4);
    short8 v1 = *(const short8*)cr;
    short8 v2 = *(const short8*)(cr + 8);
    float cf[16];
#pragma unroll
    for (int j = 0; j < 8; ++j) { cf[j] = bf2f((u16)v1[j]); cf[8 + j] = bf2f((u16)v2[j]); }
    float x = 0.f;
#pragma unroll
    for (int j = 0; j < 16; ++j) x += cf[j] * tg[j];
#pragma unroll
    for (int off = 1; off < 64; off <<= 1) x += __shfl_xor(x, off);
    if (x > m) {                       // wave-uniform after reduce
      float sc_ = __expf(m - x);
      l *= sc_;
#pragma unroll
      for (int j = 0; j < 16; ++j) acc[j] *= sc_;
      m = x;
    }
    float pv = __expf(x - m);
    l += pv;
#pragma unroll
    for (int j = 0; j < 16; ++j) acc[j] += pv * cf[j];
  };

  const int lo = half ? len2 : 0;
  const int hi = half ? len : len2;
  for (int s = lo + wave; s < hi; s += 8) process(s);

  __syncthreads();   // LDS union switch (phase A bufs / tgtf done)
  if (wave >= 1) {
#pragma unroll
    for (int j = 0; j < 16; ++j) sm.a.facc[wave - 1][fidx(lane, j)] = acc[j];
    if (lane == 0) { sm.a.fm[wave] = m; sm.a.fl[wave] = l; }
  }
  __syncthreads();
  if (wave == 0) {
#pragma unroll
    for (int w = 1; w < 8; ++w) {
      float pm2 = sm.a.fm[w], pl2 = sm.a.fl[w];
      float M = fmaxf(m, pm2);
      float e1 = __expf(m - M), e2 = __expf(pm2 - M);
#pragma unroll
      for (int j = 0; j < 16; ++j)
        acc[j] = acc[j] * e1 + sm.a.facc[w - 1][fidx(lane, j)] * e2;
      l = l * e1 + pl2 * e2;
      m = M;
    }
    if (half == 1) {                   // producer half: publish partial
      float* pa = P.pacc + (size_t)p * 1024;
#pragma unroll
      for (int j4 = 0; j4 < 4; ++j4) {
        float4 v;
        v.x = acc[j4 * 4]; v.y = acc[j4 * 4 + 1];
        v.z = acc[j4 * 4 + 2]; v.w = acc[j4 * 4 + 3];
        *(float4*)&pa[lane * 16 + j4 * 4] = v;
      }
      if (lane == 0) { P.pml[2 * p] = m; P.pml[2 * p + 1] = l; }
      asm volatile("s_waitcnt vmcnt(0)" ::: "memory");
      if (lane == 0) st_flag(P.pflag + p);
    } else {                           // consumer half: poll -> merge, else fallback
      int got = 0;
      if (lane == 0) {
        for (unsigned c2 = 0; c2 < (1u << 10); ++c2) {
          if (__hip_atomic_load(P.pflag + p, __ATOMIC_RELAXED, __HIP_MEMORY_SCOPE_AGENT) != 0) {
            got = 1; break;
          }
          __builtin_amdgcn_s_sleep(2);
        }
        if (got)
          (void)__hip_atomic_load(P.pflag + p, __ATOMIC_ACQUIRE, __HIP_MEMORY_SCOPE_AGENT);
      }
      got = __shfl(got, 0);
      if (got) {
        const float* pa = P.pacc + (size_t)p * 1024;
        float pm2 = P.pml[2 * p], pl2 = P.pml[2 * p + 1];
        float M = fmaxf(m, pm2);
        float e1 = __expf(m - M), e2 = __expf(pm2 - M);
#pragma unroll
        for (int j = 0; j < 16; ++j)
          acc[j] = acc[j] * e1 + pa[lane * 16 + j] * e2;
        l = l * e1 + pl2 * e2;
        m = M;
      } else {
        for (int s = len2; s < len; ++s) process(s);   // correct fallback
      }
      const float inv = 1.f / l;
#pragma unroll
      for (int j4 = 0; j4 < 4; ++j4) {
        ushort4 o;
        o.x = f2bf(acc[j4 * 4] * inv);
        o.y = f2bf(acc[j4 * 4 + 1] * inv);
        o.z = f2bf(acc[j4 * 4 + 2] * inv);
        o.w = f2bf(acc[j4 * 4 + 3] * inv);
        *(ushort4*)(P.wwbf + row * H_ + lane * 16 + j4 * 4) = o;
      }
    }
  }
}

// ---------------------------------------------------------------- converts (+compact +sort)
__global__ __launch_bounds__(256) void convert_all(
    const float* __restrict__ W_ih, const float* __restrict__ W_hh,
    const float* __restrict__ W_in, const float* __restrict__ W_out,
    const float* __restrict__ trg_emb, const float* __restrict__ ctx,
    const float* __restrict__ b_ih, const float* __restrict__ b_hh,
    const float* __restrict__ h0, const float* __restrict__ c0,
    const int* __restrict__ src_len,
    u16* __restrict__ wWih, u16* __restrict__ wWhh, u16* __restrict__ wWin,
    u16* __restrict__ wWout, u16* __restrict__ wemb,
    float* __restrict__ wbsum, u16* __restrict__ wh0, u16* __restrict__ whtbf,
    float* __restrict__ wc, int* __restrict__ woffs, u16* __restrict__ ctxc,
    int* __restrict__ worder) {
  __shared__ int tmp[256];
  __shared__ int skey[256];
  const int bid = blockIdx.x;
  const int tid = threadIdx.x;
  const int gtid = bid * 256 + tid;
  const int GSZ = 1024 * 256;
  for (int i = gtid; i < 1572864; i += GSZ) {     // W_ih gi (4096x1536)
    const int r = i / 384, c4 = i - r * 384;
    const int rp = ((r & 1023) << 2) + (r >> 10);
    ((ushort4*)wWih)[(size_t)rp * 384 + c4] = cvt4bf(((const float4*)W_ih)[i]);
  }
  for (int i = gtid; i < 1048576; i += GSZ) {     // W_hh gi (4096x1024)
    const int r = i >> 8, c4 = i & 255;
    const int rp = ((r & 1023) << 2) + (r >> 10);
    ((ushort4*)wWhh)[(size_t)rp * 256 + c4] = cvt4bf(((const float4*)W_hh)[i]);
  }
  for (int i = gtid; i < 262144; i += GSZ)        // W_in (1024x1024)
    ((ushort4*)wWin)[i] = cvt4bf(((const float4*)W_in)[i]);
  for (int i = gtid; i < 524288; i += GSZ)        // W_out (1024x2048)
    ((ushort4*)wWout)[i] = cvt4bf(((const float4*)W_out)[i]);
  for (int i = gtid; i < 524288; i += GSZ)        // emb (B,T,E)
    ((ushort4*)wemb)[i] = cvt4bf(((const float4*)trg_emb)[i]);
  if (gtid < 4096) {                              // bias (gi)
    const int cp = ((gtid & 1023) << 2) + (gtid >> 10);
    wbsum[cp] = b_ih[gtid] + b_hh[gtid];
  }
  for (int i = gtid; i < 262144; i += GSZ) {      // state init
    u16 hb = f2bf(h0[i]);
    wh0[i] = hb;
    whtbf[i] = hb;
    wc[i] = c0[i];
  }
  if (bid >= 768) {                               // ctx compaction (256 blocks)
    const int b = bid - 768;
    tmp[tid] = (tid < b) ? src_len[tid] : 0;
    __syncthreads();
    for (int o = 128; o > 0; o >>= 1) {
      if (tid < o) tmp[tid] += tmp[tid + o];
      __syncthreads();
    }
    const int off = tmp[0];
    if (tid == 0) woffs[b] = off;
    const int n4 = src_len[b] << 8;
    const float4* s = (const float4*)(ctx + ((size_t)b << 19));
    ushort4* d = (ushort4*)(ctxc + ((size_t)off << 10));
    for (int i = tid; i < n4; i += 256) d[i] = cvt4bf(s[i]);
  }
  if (bid == 0) {                                 // length sort -> worder
    skey[tid] = (src_len[tid] << 16) | tid;
    __syncthreads();
    for (int k = 2; k <= 256; k <<= 1) {
      for (int j = k >> 1; j > 0; j >>= 1) {
        const int ixj = tid ^ j;
        if (ixj > tid) {
          int a = skey[tid], b = skey[ixj];
          bool asc = ((tid & k) == 0);
          if ((a > b) == asc) { skey[tid] = b; skey[ixj] = a; }
        }
        __syncthreads();
      }
    }
    // pairs 0..31 (the W_in blocks) get the 32 shortest rows;
    // pairs 32..255 get the rest longest-first.
    worder[tid] = (tid < 32 ? skey[tid] : skey[287 - tid]) & 0xFFFF;
  }
}

// ---------------------------------------------------------------- host
extern "C" void kernel_launch(void* const* d_in, const int* in_sizes, int n_in,
                              void* d_out, int out_size, void* d_ws, size_t ws_size,
                              hipStream_t stream) {
  const float* trg_emb = (const float*)d_in[0];
  const float* h0      = (const float*)d_in[1];
  const float* c0      = (const float*)d_in[2];
  const float* ctx     = (const float*)d_in[3];
  const int*   src_len = (const int*)d_in[4];
  const float* W_ih    = (const float*)d_in[5];
  const float* W_hh    = (const float*)d_in[6];
  const float* b_ih    = (const float*)d_in[7];
  const float* b_hh    = (const float*)d_in[8];
  const float* W_in    = (const float*)d_in[9];
  const float* W_out   = (const float*)d_in[10];
  float* out = (float*)d_out;

  char* w = (char*)d_ws;
  size_t off = 0;
  auto alloc = [&](size_t bytes) { char* p = w + off; off += bytes; return p; };
  u16*   wWih   = (u16*)  alloc(12582912);
  u16*   wWhh   = (u16*)  alloc(8388608);
  u16*   wWin   = (u16*)  alloc(2097152);
  u16*   wWout  = (u16*)  alloc(4194304);
  u16*   wemb   = (u16*)  alloc(4194304);
  float* wbsum  = (float*)alloc(16384);
  float* wc     = (float*)alloc(1048576);
  u16*   wh0    = (u16*)  alloc(524288);
  u16*   wh1    = (u16*)  alloc(524288);
  u16*   whtbf  = (u16*)  alloc(524288);
  u16*   wwbf   = (u16*)  alloc(524288);
  int*   woffs  = (int*)  alloc(1024);
  int*   worder = (int*)  alloc(1024);
  int*   flags  = (int*)  alloc(20480);      // 16*64 tflags + 16*256 pflags
  u16*   wtgt16 = (u16*)  alloc(8388608);    // per-step target
  float* pacc16 = (float*)alloc(16777216);   // per-step pair partials
  float* pml16  = (float*)alloc(32768);
  u16*   wctxc  = (u16*)  alloc(268435456);
  (void)ws_size;
  int* tflags = flags;             // [16][64]
  int* pflags = flags + 16 * 64;   // [16][256]

  hipMemsetAsync(flags, 0, 20480, stream);
  convert_all<<<dim3(1024), dim3(256), 0, stream>>>(
      W_ih, W_hh, W_in, W_out, trg_emb, ctx, b_ih, b_hh, h0, c0, src_len,
      wWih, wWhh, wWin, wWout, wemb, wbsum, wh0, whtbf, wc, woffs, wctxc, worder);

  Reg3 rz = { nullptr, 0, nullptr, 0, 0 };
  for (int t = 0; t < T_; ++t) {
    const u16* hcur = (t & 1) ? wh1 : wh0;
    u16* hnxt = (t & 1) ? wh0 : wh1;
    // gates = [emb_t | htilde | h] @ [W_ihE | W_ihH | W_hh]^T (+bias) -> LSTM
    Reg3 g0 = { wemb + (size_t)t * E_, T_ * E_, wWih,      E_ + H_, 8 };
    Reg3 g1 = { whtbf,                 H_,      wWih + E_, E_ + H_, 16 };
    Reg3 g2 = { hcur,                  H_,      wWhh,      H_,      16 };
    gemm_k<3><<<dim3(256), dim3(256), 0, stream>>>(
        g0, g1, g2, 4, nullptr, nullptr, wbsum, wc, hnxt,
        (t == T_ - 1) ? out + (size_t)B_ * T_ * H_ : nullptr, 0);
    // fused: W_in GEMM (blocks 0..63) + paired online-softmax attention
    AP ap;
    ap.hrow = hnxt; ap.Win = wWin;
    ap.tgt = wtgt16 + (size_t)t * 262144;
    ap.ctxc = wctxc; ap.woffs = woffs; ap.src_len = src_len; ap.worder = worder;
    ap.wwbf = wwbf;
    ap.pacc = pacc16 + (size_t)t * 262144;
    ap.pml = pml16 + t * 512;
    ap.tflag = tflags + t * 64;
    ap.pflag = pflags + t * 256;
    attn_fused<<<dim3(512), dim3(512), 0, stream>>>(ap);
    // htilde = tanh([weighted | h] @ W_out^T) -> out[:,t,:] + feedback
    Reg3 o0 = { wwbf, H_, wWout,      2 * H_, 16 };
    Reg3 o1 = { hnxt, H_, wWout + H_, 2 * H_, 16 };
    gemm_k<2><<<dim3(64), dim3(256), 0, stream>>>(
        o0, o1, rz, 4, out, whtbf, nullptr, nullptr, nullptr, nullptr, t);
  }
}

// Round 14
// 1910.637 us; speedup vs baseline: 1.0587x; 1.0587x over previous
//
#include <hip/hip_runtime.h>
#include <cstdint>
#include <cstddef>

// CCDecoder: 16-step input-feeding LSTM + Luong attention decoder.
// B=256, S=512, T=16, H=1024, E=512.
// R14 = R12 (best measured: 1914us) + flag-memset folded into convert_all
//   (-1 graph node). R13's W_in fusion regressed (+108us): in-kernel flag
//   sync (~27us) >= node boundary (~20us) -- 5-way sync experiment matrix
//   (cg 50us / atomic-bar 50us / flags 41us / fused-flags 27us / node 20us)
//   establishes graph-node boundaries as the cheapest cross-XCD ordering.
//   Structure: multi-launch, 4 nodes/step x 16 steps + 1 convert node.
//   - gates/W_in/W_out GEMM: 64x64 tile, 4 waves (2x2, 32x32 acc/wave),
//     NBUF=6, 4-deep prefetch, counted vmcnt(16/12/8/4/0), XOR-swizzled LDS
//     (both sides), fused LSTM epilogue (gate-interleaved weights).
//   - attn: 512 blocks x 512 thr; pair (2p,2p+1) = halves of row p; online
//     softmax; producer half publishes (m,l,acc)+release-flag; consumer
//     polls (capped) with compute-it-yourself fallback (deadlock-impossible).
//   - ctx compacted (rows s<len) to bf16 -> L3-resident.
//   - h ping-pong; final h,c written by t==15 gates epilogue.

#define B_ 256
#define S_ 512
#define T_ 16
#define H_ 1024
#define E_ 512
#define NBUF 6

typedef unsigned short u16;
using short8 = __attribute__((ext_vector_type(8))) short;
using f32x4  = __attribute__((ext_vector_type(4))) float;

__device__ __forceinline__ float bf2f(u16 u) {
  union { uint32_t i; float f; } v; v.i = ((uint32_t)u) << 16; return v.f;
}
__device__ __forceinline__ u16 f2bf(float f) {
  union { uint32_t i; float f; } v; v.f = f;
  uint32_t r = v.i + 0x7fffu + ((v.i >> 16) & 1u);
  return (u16)(r >> 16);
}
__device__ __forceinline__ ushort4 cvt4bf(float4 v) {
  ushort4 o; o.x = f2bf(v.x); o.y = f2bf(v.y); o.z = f2bf(v.z); o.w = f2bf(v.w);
  return o;
}
__device__ __forceinline__ float sigmoidf_(float x) { return 1.f / (1.f + __expf(-x)); }

__device__ __forceinline__ void gload_lds16(const void* g, void* l) {
  __builtin_amdgcn_global_load_lds(
      (const __attribute__((address_space(1))) void*)g,
      (__attribute__((address_space(3))) void*)l, 16, 0, 0);
}

struct Reg3 { const u16* A; int lda; const u16* B; int ldb; int kt; };

// ---------------------------------------------------------------- GEMM
// 64x64 tile, 256 thr = 4 waves (2x2), 32x32 acc/wave (acc[2][2]).
// NBUF=6, 4-deep prefetch, counted vmcnt (4 loads/thread/stage).
// Safety: stage(k) issues between barrier(k-5)/(k-4); concurrent readers
// j in {k-5,k-4}; buffer distance 5,4 mod 6 != 0.
template <int EPI>   // 1: bf16->Cb  2: tanh->fp32 out+bf16 Cb  3: fused LSTM
__global__ __launch_bounds__(256) void gemm_k(Reg3 r0, Reg3 r1, Reg3 r2,
                                              int nmb,
                                              float* __restrict__ Cf,
                                              u16* __restrict__ Cb,
                                              const float* __restrict__ bsum,
                                              float* __restrict__ cst,
                                              u16* __restrict__ hbfo,
                                              float* __restrict__ outHC,
                                              const int tstep) {
  __shared__ u16 smA[NBUF][4096];
  __shared__ u16 smB[NBUF][4096];
  const int tid = threadIdx.x;
  const int lane = tid & 63;
  const int wave = tid >> 6;
  const int wm = wave >> 1, wn = wave & 1;
  const int m0 = (blockIdx.x % nmb) * 64;
  const int n0 = (blockIdx.x / nmb) * 64;
  const int row16 = lane & 15;
  const int kg = lane >> 4;
  const int nt = r0.kt + r1.kt + r2.kt;

  auto stage = [&](int ti, int buf) {
    const int k01 = r0.kt + r1.kt;
    const u16* Ap = (ti < r0.kt) ? r0.A : (ti < k01) ? r1.A : r2.A;
    const u16* Bp = (ti < r0.kt) ? r0.B : (ti < k01) ? r1.B : r2.B;
    const int lda = (ti < r0.kt) ? r0.lda : (ti < k01) ? r1.lda : r2.lda;
    const int ldb = (ti < r0.kt) ? r0.ldb : (ti < k01) ? r1.ldb : r2.ldb;
    const int base = (ti < r0.kt) ? 0 : (ti < k01) ? r0.kt : k01;
    const int kr = (ti - base) << 6;
#pragma unroll
    for (int j = 0; j < 2; ++j) {   // A: 64x64 = 512 chunks, 2/thread
      const int c = j * 256 + tid;
      const int row = c >> 3, q = c & 7;
      gload_lds16(Ap + (size_t)(m0 + row) * lda + kr + ((q ^ (row & 7)) << 3),
                  (char*)&smA[buf][0] + (size_t)(j * 256 + wave * 64) * 16);
    }
#pragma unroll
    for (int j = 0; j < 2; ++j) {   // B: 64x64 = 512 chunks, 2/thread
      const int c = j * 256 + tid;
      const int row = c >> 3, q = c & 7;
      gload_lds16(Bp + (size_t)(n0 + row) * ldb + kr + ((q ^ (row & 7)) << 3),
                  (char*)&smB[buf][0] + (size_t)(j * 256 + wave * 64) * 16);
    }
  };

  f32x4 acc[2][2] = {};
  stage(0, 0);
  if (nt > 1) stage(1, 1);
  if (nt > 2) stage(2, 2);
  if (nt > 3) stage(3, 3);
  for (int ti = 0; ti < nt; ++ti) {
    const int buf = ti % NBUF;
    if (ti + 4 < nt) {
      stage(ti + 4, (ti + 4) % NBUF);
      asm volatile("s_waitcnt vmcnt(16)" ::: "memory");
    } else if (ti + 3 < nt) {
      asm volatile("s_waitcnt vmcnt(12)" ::: "memory");
    } else if (ti + 2 < nt) {
      asm volatile("s_waitcnt vmcnt(8)" ::: "memory");
    } else if (ti + 1 < nt) {
      asm volatile("s_waitcnt vmcnt(4)" ::: "memory");
    } else {
      asm volatile("s_waitcnt vmcnt(0)" ::: "memory");
    }
    __builtin_amdgcn_s_barrier();
    __builtin_amdgcn_sched_barrier(0);
#pragma unroll
    for (int ks = 0; ks < 2; ++ks) {
      short8 af[2], bfr[2];
#pragma unroll
      for (int mi = 0; mi < 2; ++mi) {
        const int R = wm * 32 + mi * 16 + row16;
        af[mi] = *(const short8*)((const char*)&smA[buf][0] +
                                  (size_t)(((R << 3) | ((ks * 4 + kg) ^ (R & 7))) << 4));
      }
#pragma unroll
      for (int ni = 0; ni < 2; ++ni) {
        const int R = wn * 32 + ni * 16 + row16;
        bfr[ni] = *(const short8*)((const char*)&smB[buf][0] +
                                   (size_t)(((R << 3) | ((ks * 4 + kg) ^ (R & 7))) << 4));
      }
      asm volatile("s_waitcnt lgkmcnt(0)" ::: "memory");
      __builtin_amdgcn_sched_barrier(0);
#pragma unroll
      for (int mi = 0; mi < 2; ++mi)
#pragma unroll
        for (int ni = 0; ni < 2; ++ni)
          acc[mi][ni] = __builtin_amdgcn_mfma_f32_16x16x32_bf16(af[mi], bfr[ni], acc[mi][ni], 0, 0, 0);
      __builtin_amdgcn_sched_barrier(0);
    }
  }
  // C/D layout: col = lane&15, row = (lane>>4)*4 + r  [m89-verified]
#pragma unroll
  for (int mi = 0; mi < 2; ++mi) {
#pragma unroll
    for (int ni = 0; ni < 2; ++ni) {
#pragma unroll
      for (int r = 0; r < 4; ++r) {
        const int row = m0 + wm * 32 + mi * 16 + (kg << 2) + r;
        const int col = n0 + wn * 32 + ni * 16 + row16;
        float v = acc[mi][ni][r];
        if (EPI == 1) {
          Cb[row * H_ + col] = f2bf(v);
        } else if (EPI == 2) {
          float tv = tanhf(v);
          Cf[(size_t)row * (T_ * H_) + (size_t)tstep * H_ + col] = tv;
          Cb[row * H_ + col] = f2bf(tv);
        } else {
          // gate-interleaved: col&3 = gate(i,f,g,o), col>>2 = unit
          v += bsum[col];
          float v1 = __shfl_xor(v, 1);
          float v2 = __shfl_xor(v, 2);
          float v3 = __shfl_xor(v, 3);
          if ((lane & 3) == 0) {
            const int u = col >> 2;
            float iv = sigmoidf_(v);
            float fv = sigmoidf_(v1);
            float gv = tanhf(v2);
            float ov = sigmoidf_(v3);
            float cn = fv * cst[row * H_ + u] + iv * gv;
            float hn = ov * tanhf(cn);
            cst[row * H_ + u] = cn;
            hbfo[row * H_ + u] = f2bf(hn);
            if (outHC) {                     // t==15: final h,c directly
              outHC[row * H_ + u] = hn;
              outHC[B_ * H_ + row * H_ + u] = cn;
            }
          }
        }
      }
    }
  }
}

// ---------------------------------------------------------------- attention
// 512 blocks x 512 thr (8 waves). Pair (2p, 2p+1) = halves of row p.
// Odd block: partial (m,l,acc) -> ws + release flag. Even block: own half,
// poll (capped) -> merge; on cap expiry FALL BACK to computing the odd half
// itself (correct regardless of scheduling).
__device__ __forceinline__ int fidx(int lane, int j) {
  return (j << 6) + ((lane + (j << 2)) & 63);
}

__global__ __launch_bounds__(512, 4) void attn_pair(const u16* __restrict__ tgt,
                                                    const u16* __restrict__ ctxc,
                                                    const int* __restrict__ woffs,
                                                    const int* __restrict__ src_len,
                                                    u16* __restrict__ wwbf,
                                                    float* __restrict__ pacc,
                                                    float* __restrict__ pml,
                                                    int* __restrict__ flag) {
  __shared__ float facc[7][1024];
  __shared__ float fm[8], fl[8];
  const int p = blockIdx.x >> 1;
  const int half = blockIdx.x & 1;
  const int tid = threadIdx.x;
  const int lane = tid & 63;
  const int wave = tid >> 6;           // 0..7
  const int len = src_len[p];
  const int len2 = (len + 1) >> 1;
  const u16* cb = ctxc + ((size_t)woffs[p] << 10);

  float tg[16];
  {
    const u16* tp = tgt + p * H_ + lane * 16;
    short8 v1 = *(const short8*)tp;
    short8 v2 = *(const short8*)(tp + 8);
#pragma unroll
    for (int j = 0; j < 8; ++j) { tg[j] = bf2f((u16)v1[j]); tg[8 + j] = bf2f((u16)v2[j]); }
  }
  float m = -1e30f, l = 0.f;
  float acc[16];
#pragma unroll
  for (int j = 0; j < 16; ++j) acc[j] = 0.f;

  auto process = [&](int s) {
    const u16* cr = cb + ((size_t)s << 10) + (lane << 4);
    short8 v1 = *(const short8*)cr;
    short8 v2 = *(const short8*)(cr + 8);
    float cf[16];
#pragma unroll
    for (int j = 0; j < 8; ++j) { cf[j] = bf2f((u16)v1[j]); cf[8 + j] = bf2f((u16)v2[j]); }
    float x = 0.f;
#pragma unroll
    for (int j = 0; j < 16; ++j) x += cf[j] * tg[j];
#pragma unroll
    for (int off = 1; off < 64; off <<= 1) x += __shfl_xor(x, off);
    if (x > m) {                       // wave-uniform after reduce
      float sc_ = __expf(m - x);
      l *= sc_;
#pragma unroll
      for (int j = 0; j < 16; ++j) acc[j] *= sc_;
      m = x;
    }
    float pv = __expf(x - m);
    l += pv;
#pragma unroll
    for (int j = 0; j < 16; ++j) acc[j] += pv * cf[j];
  };

  const int lo = half ? len2 : 0;
  const int hi = half ? len : len2;
  for (int s = lo + wave; s < hi; s += 8) process(s);

  // merge 8 wave-partials into wave 0
  if (wave >= 1) {
#pragma unroll
    for (int j = 0; j < 16; ++j) facc[wave - 1][fidx(lane, j)] = acc[j];
    if (lane == 0) { fm[wave] = m; fl[wave] = l; }
  }
  __syncthreads();
  if (wave == 0) {
#pragma unroll
    for (int w = 1; w < 8; ++w) {
      float pm2 = fm[w], pl2 = fl[w];
      float M = fmaxf(m, pm2);
      float e1 = __expf(m - M), e2 = __expf(pm2 - M);
#pragma unroll
      for (int j = 0; j < 16; ++j)
        acc[j] = acc[j] * e1 + facc[w - 1][fidx(lane, j)] * e2;
      l = l * e1 + pl2 * e2;
      m = M;
    }
    if (half == 1) {                   // producer: publish partial
      float* pa = pacc + (size_t)p * 1024;
#pragma unroll
      for (int j4 = 0; j4 < 4; ++j4) {
        float4 v;
        v.x = acc[j4 * 4]; v.y = acc[j4 * 4 + 1];
        v.z = acc[j4 * 4 + 2]; v.w = acc[j4 * 4 + 3];
        *(float4*)&pa[lane * 16 + j4 * 4] = v;
      }
      if (lane == 0) { pml[2 * p] = m; pml[2 * p + 1] = l; }
      asm volatile("s_waitcnt vmcnt(0)" ::: "memory");
      if (lane == 0)
        __hip_atomic_store(flag + p, 1, __ATOMIC_RELEASE, __HIP_MEMORY_SCOPE_AGENT);
    } else {                           // consumer: poll -> merge, else fallback
      int got = 0;
      if (lane == 0) {
        for (unsigned c2 = 0; c2 < (1u << 10); ++c2) {
          if (__hip_atomic_load(flag + p, __ATOMIC_RELAXED, __HIP_MEMORY_SCOPE_AGENT) != 0) {
            got = 1; break;
          }
          __builtin_amdgcn_s_sleep(2);
        }
        if (got)
          (void)__hip_atomic_load(flag + p, __ATOMIC_ACQUIRE, __HIP_MEMORY_SCOPE_AGENT);
      }
      got = __shfl(got, 0);
      if (got) {
        const float* pa = pacc + (size_t)p * 1024;
        float pm2 = pml[2 * p], pl2 = pml[2 * p + 1];
        float M = fmaxf(m, pm2);
        float e1 = __expf(m - M), e2 = __expf(pm2 - M);
#pragma unroll
        for (int j = 0; j < 16; ++j)
          acc[j] = acc[j] * e1 + pa[lane * 16 + j] * e2;
        l = l * e1 + pl2 * e2;
        m = M;
      } else {
        for (int s = len2; s < len; ++s) process(s);   // correct fallback
      }
      const float inv = 1.f / l;
#pragma unroll
      for (int j4 = 0; j4 < 4; ++j4) {
        ushort4 o;
        o.x = f2bf(acc[j4 * 4] * inv);
        o.y = f2bf(acc[j4 * 4 + 1] * inv);
        o.z = f2bf(acc[j4 * 4 + 2] * inv);
        o.w = f2bf(acc[j4 * 4 + 3] * inv);
        *(ushort4*)(wwbf + p * H_ + lane * 16 + j4 * 4) = o;
      }
    }
  }
}

// ---------------------------------------------------------------- converts (+compact +flag-zero)
__global__ __launch_bounds__(256) void convert_all(
    const float* __restrict__ W_ih, const float* __restrict__ W_hh,
    const float* __restrict__ W_in, const float* __restrict__ W_out,
    const float* __restrict__ trg_emb, const float* __restrict__ ctx,
    const float* __restrict__ b_ih, const float* __restrict__ b_hh,
    const float* __restrict__ h0, const float* __restrict__ c0,
    const int* __restrict__ src_len,
    u16* __restrict__ wWih, u16* __restrict__ wWhh, u16* __restrict__ wWin,
    u16* __restrict__ wWout, u16* __restrict__ wemb,
    float* __restrict__ wbsum, u16* __restrict__ wh0, u16* __restrict__ whtbf,
    float* __restrict__ wc, int* __restrict__ woffs, u16* __restrict__ ctxc,
    int* __restrict__ wflag) {
  __shared__ int tmp[256];
  const int bid = blockIdx.x;
  const int tid = threadIdx.x;
  const int gtid = bid * 256 + tid;
  const int GSZ = 1024 * 256;
  for (int i = gtid; i < 1572864; i += GSZ) {     // W_ih gi (4096x1536)
    const int r = i / 384, c4 = i - r * 384;
    const int rp = ((r & 1023) << 2) + (r >> 10);
    ((ushort4*)wWih)[(size_t)rp * 384 + c4] = cvt4bf(((const float4*)W_ih)[i]);
  }
  for (int i = gtid; i < 1048576; i += GSZ) {     // W_hh gi (4096x1024)
    const int r = i >> 8, c4 = i & 255;
    const int rp = ((r & 1023) << 2) + (r >> 10);
    ((ushort4*)wWhh)[(size_t)rp * 256 + c4] = cvt4bf(((const float4*)W_hh)[i]);
  }
  for (int i = gtid; i < 262144; i += GSZ)        // W_in (1024x1024)
    ((ushort4*)wWin)[i] = cvt4bf(((const float4*)W_in)[i]);
  for (int i = gtid; i < 524288; i += GSZ)        // W_out (1024x2048)
    ((ushort4*)wWout)[i] = cvt4bf(((const float4*)W_out)[i]);
  for (int i = gtid; i < 524288; i += GSZ)        // emb (B,T,E)
    ((ushort4*)wemb)[i] = cvt4bf(((const float4*)trg_emb)[i]);
  if (gtid < 4096) {                              // bias (gi)
    const int cp = ((gtid & 1023) << 2) + (gtid >> 10);
    wbsum[cp] = b_ih[gtid] + b_hh[gtid];
  }
  if (gtid < 4096) wflag[gtid] = 0;               // 16 steps x 256 pair flags
  for (int i = gtid; i < 262144; i += GSZ) {      // state init
    u16 hb = f2bf(h0[i]);
    wh0[i] = hb;
    whtbf[i] = hb;
    wc[i] = c0[i];
  }
  if (bid >= 768) {                               // ctx compaction (256 blocks)
    const int b = bid - 768;
    tmp[tid] = (tid < b) ? src_len[tid] : 0;
    __syncthreads();
    for (int o = 128; o > 0; o >>= 1) {
      if (tid < o) tmp[tid] += tmp[tid + o];
      __syncthreads();
    }
    const int off = tmp[0];
    if (tid == 0) woffs[b] = off;
    const int n4 = src_len[b] << 8;               // len*1024/4 vec4s
    const float4* s = (const float4*)(ctx + ((size_t)b << 19));
    ushort4* d = (ushort4*)(ctxc + ((size_t)off << 10));
    for (int i = tid; i < n4; i += 256) d[i] = cvt4bf(s[i]);
  }
}

// ---------------------------------------------------------------- host
extern "C" void kernel_launch(void* const* d_in, const int* in_sizes, int n_in,
                              void* d_out, int out_size, void* d_ws, size_t ws_size,
                              hipStream_t stream) {
  const float* trg_emb = (const float*)d_in[0];
  const float* h0      = (const float*)d_in[1];
  const float* c0      = (const float*)d_in[2];
  const float* ctx     = (const float*)d_in[3];
  const int*   src_len = (const int*)d_in[4];
  const float* W_ih    = (const float*)d_in[5];
  const float* W_hh    = (const float*)d_in[6];
  const float* b_ih    = (const float*)d_in[7];
  const float* b_hh    = (const float*)d_in[8];
  const float* W_in    = (const float*)d_in[9];
  const float* W_out   = (const float*)d_in[10];
  float* out = (float*)d_out;

  char* w = (char*)d_ws;
  size_t off = 0;
  auto alloc = [&](size_t bytes) { char* p = w + off; off += bytes; return p; };
  u16*   wWih  = (u16*)  alloc(12582912);   // 4096x1536 bf16 (gi rows)
  u16*   wWhh  = (u16*)  alloc(8388608);    // 4096x1024 bf16 (gi rows)
  u16*   wWin  = (u16*)  alloc(2097152);    // 1024x1024
  u16*   wWout = (u16*)  alloc(4194304);    // 1024x2048
  u16*   wemb  = (u16*)  alloc(4194304);    // (B,T,E) bf16
  float* wbsum = (float*)alloc(16384);
  float* wc    = (float*)alloc(1048576);
  u16*   wh0   = (u16*)  alloc(524288);     // h ping
  u16*   wh1   = (u16*)  alloc(524288);     // h pong
  u16*   whtbf = (u16*)  alloc(524288);
  u16*   wtgt  = (u16*)  alloc(524288);
  u16*   wwbf  = (u16*)  alloc(524288);
  int*   woffs = (int*)  alloc(1024);
  int*   wflag = (int*)  alloc(16384);      // 16 steps x 256 pair flags
  float* pacc  = (float*)alloc(1048576);    // 256 x 1024 partial acc
  float* pml   = (float*)alloc(2048);       // 256 x (m,l)
  u16*   wctxc = (u16*)  alloc(268435456);  // compacted ctx bf16 (worst case)
  (void)ws_size;

  convert_all<<<dim3(1024), dim3(256), 0, stream>>>(
      W_ih, W_hh, W_in, W_out, trg_emb, ctx, b_ih, b_hh, h0, c0, src_len,
      wWih, wWhh, wWin, wWout, wemb, wbsum, wh0, whtbf, wc, woffs, wctxc, wflag);

  Reg3 rz = { nullptr, 0, nullptr, 0, 0 };
  for (int t = 0; t < T_; ++t) {
    const u16* hcur = (t & 1) ? wh1 : wh0;
    u16* hnxt = (t & 1) ? wh0 : wh1;
    // gates = [emb_t | htilde | h] @ [W_ihE | W_ihH | W_hh]^T (+bias) -> LSTM
    Reg3 g0 = { wemb + (size_t)t * E_, T_ * E_, wWih,      E_ + H_, 8 };
    Reg3 g1 = { whtbf,                 H_,      wWih + E_, E_ + H_, 16 };
    Reg3 g2 = { hcur,                  H_,      wWhh,      H_,      16 };
    gemm_k<3><<<dim3(256), dim3(256), 0, stream>>>(
        g0, g1, g2, 4, nullptr, nullptr, wbsum, wc, hnxt,
        (t == T_ - 1) ? out + (size_t)B_ * T_ * H_ : nullptr, 0);
    // target = h @ W_in^T  (M=256, N=1024, K=1024)
    Reg3 i0 = { hnxt, H_, wWin, H_, 16 };
    gemm_k<1><<<dim3(64), dim3(256), 0, stream>>>(
        i0, rz, rz, 4, nullptr, wtgt, nullptr, nullptr, nullptr, nullptr, 0);
    // attn: paired half-rows, online softmax, pairwise flag merge
    attn_pair<<<dim3(512), dim3(512), 0, stream>>>(
        wtgt, wctxc, woffs, src_len, wwbf, pacc, pml, wflag + t * 256);
    // htilde = tanh([weighted | h] @ W_out^T) -> out[:,t,:] + feedback
    Reg3 o0 = { wwbf, H_, wWout,      2 * H_, 16 };
    Reg3 o1 = { hnxt, H_, wWout + H_, 2 * H_, 16 };
    gemm_k<2><<<dim3(64), dim3(256), 0, stream>>>(
        o0, o1, rz, 4, out, whtbf, nullptr, nullptr, nullptr, nullptr, t);
  }
}